// Round 1
// baseline (8746.637 us; speedup 1.0000x reference)
//
#include <hip/hip_runtime.h>
#include <hip/hip_bf16.h>

#define N_NODES 50000
#define N_EDGES 800000
#define F_IN    128
#define H_DIM   256
#define G_NUM   64
#define A_DIM   8

// ---------------- small utility kernels ----------------

__global__ void fill_kernel(float* __restrict__ p, float v, int n) {
    int i = blockIdx.x * blockDim.x + threadIdx.x;
    if (i < n) p[i] = v;
}

__global__ void deg_kernel(const int* __restrict__ dst, float* __restrict__ deg, int e) {
    int i = blockIdx.x * blockDim.x + threadIdx.x;
    if (i < e) atomicAdd(&deg[dst[i]], 1.0f);
}

__global__ void dinv_kernel(float* __restrict__ deg, int n) {
    int i = blockIdx.x * blockDim.x + threadIdx.x;
    if (i < n) {
        float d = deg[i];
        deg[i] = (d > 0.f) ? rsqrtf(d) : 0.f;
    }
}

// ---------------- SGEMM: C[M,256] = A[M,K] @ B[K,256] (row-major, no bias) ----

__global__ __launch_bounds__(256) void sgemm64(const float* __restrict__ A,
                                               const float* __restrict__ B,
                                               float* __restrict__ C,
                                               int M, int K) {
    // BM=64, BN=64, BK=16; 16x16 threads, 4x4 micro-tile per thread.
    __shared__ float As[16][68];   // +4 pad: store bank = (4k+m)%32 -> 2-way max (free)
    __shared__ float Bs[16][64];
    int tid = threadIdx.x;
    int tx = tid & 15, ty = tid >> 4;
    int bm = blockIdx.x * 64;
    int bn = blockIdx.y * 64;
    float acc[4][4] = {};
    for (int k0 = 0; k0 < K; k0 += 16) {
        {   // A tile 64x16 -> As[k][m]
            int k = tid & 15;
            int m0 = tid >> 4;
            #pragma unroll
            for (int i = 0; i < 4; i++) {
                int m = m0 + i * 16;
                int row = bm + m;
                As[k][m] = (row < M) ? A[(size_t)row * K + k0 + k] : 0.f;
            }
        }
        {   // B tile 16x64 -> Bs[k][n]
            int n = tid & 63;
            int k1 = tid >> 6;
            #pragma unroll
            for (int i = 0; i < 4; i++) {
                int k = k1 + i * 4;
                Bs[k][n] = B[(size_t)(k0 + k) * H_DIM + bn + n];
            }
        }
        __syncthreads();
        #pragma unroll
        for (int k = 0; k < 16; k++) {
            float4 a = *(const float4*)&As[k][ty * 4];
            float4 b = *(const float4*)&Bs[k][tx * 4];
            float av[4] = {a.x, a.y, a.z, a.w};
            float bv[4] = {b.x, b.y, b.z, b.w};
            #pragma unroll
            for (int i = 0; i < 4; i++)
                #pragma unroll
                for (int j = 0; j < 4; j++)
                    acc[i][j] += av[i] * bv[j];
        }
        __syncthreads();
    }
    #pragma unroll
    for (int i = 0; i < 4; i++) {
        int row = bm + ty * 4 + i;
        if (row < M) {
            float4 v = make_float4(acc[i][0], acc[i][1], acc[i][2], acc[i][3]);
            *(float4*)&C[(size_t)row * H_DIM + bn + tx * 4] = v;
        }
    }
}

// ---------------- GCN aggregation ----------------

// agg[i] = dinv[i]^2 * xw[i]  (self-loop term; also initializes poisoned buffer)
__global__ void selfloop_kernel(const float* __restrict__ xw, float* __restrict__ agg,
                                const float* __restrict__ dinv, int n) {
    size_t i = (size_t)blockIdx.x * blockDim.x + threadIdx.x;  // over n*64 float4s
    if (i >= (size_t)n * (H_DIM / 4)) return;
    int node = (int)(i >> 6);
    float d = dinv[node];
    float w = d * d;
    float4 v = ((const float4*)xw)[i];
    v.x *= w; v.y *= w; v.z *= w; v.w *= w;
    ((float4*)agg)[i] = v;
}

// one wave (64 lanes) per edge; 4 floats per lane
__global__ __launch_bounds__(256) void scatter_kernel(const float* __restrict__ xw,
                                                      float* __restrict__ agg,
                                                      const int* __restrict__ src,
                                                      const int* __restrict__ dst,
                                                      const float* __restrict__ dinv,
                                                      int e) {
    int eidx = blockIdx.x * 4 + (threadIdx.x >> 6);
    if (eidx >= e) return;
    int lane = threadIdx.x & 63;
    int s = src[eidx], d = dst[eidx];
    float nrm = dinv[s] * dinv[d];
    float4 v = ((const float4*)(xw + (size_t)s * H_DIM))[lane];
    float* ad = agg + (size_t)d * H_DIM + lane * 4;
    atomicAdd(ad + 0, v.x * nrm);
    atomicAdd(ad + 1, v.y * nrm);
    atomicAdd(ad + 2, v.z * nrm);
    atomicAdd(ad + 3, v.w * nrm);
}

// ---------------- LayerNorm(+bias pre-LN) + ReLU, in-place, one block per row ----

__global__ __launch_bounds__(256) void ln_relu_kernel(float* __restrict__ h,
                                                      const float* __restrict__ bias,
                                                      const float* __restrict__ gamma,
                                                      const float* __restrict__ beta) {
    int row = blockIdx.x;
    int t = threadIdx.x;
    float v = h[(size_t)row * H_DIM + t] + bias[t];
    float s = v, ss = v * v;
    #pragma unroll
    for (int o = 32; o; o >>= 1) {
        s  += __shfl_down(s, o, 64);
        ss += __shfl_down(ss, o, 64);
    }
    __shared__ float rs[4], rss[4];
    __shared__ float mean_s, rstd_s;
    int wid = t >> 6, lane = t & 63;
    if (lane == 0) { rs[wid] = s; rss[wid] = ss; }
    __syncthreads();
    if (t == 0) {
        float S  = rs[0] + rs[1] + rs[2] + rs[3];
        float SS = rss[0] + rss[1] + rss[2] + rss[3];
        float m = S * (1.f / H_DIM);
        float var = SS * (1.f / H_DIM) - m * m;
        mean_s = m;
        rstd_s = rsqrtf(var + 1e-5f);
    }
    __syncthreads();
    float o = (v - mean_s) * rstd_s * gamma[t] + beta[t];
    h[(size_t)row * H_DIM + t] = fmaxf(o, 0.f);
}

// ---------------- pooling ----------------

// block handles 64 consecutive nodes; thread t accumulates feature t, flushing
// on graph-id change (batch is sorted -> ~1 flush per block)
__global__ __launch_bounds__(256) void pool_kernel(const float* __restrict__ h,
                                                   const int* __restrict__ batch,
                                                   float* __restrict__ pooled, int n) {
    int t = threadIdx.x;
    int start = blockIdx.x * 64;
    int end = min(start + 64, n);
    if (start >= n) return;
    int cur = batch[start];
    float acc = 0.f;
    for (int i = start; i < end; ++i) {
        int g = batch[i];
        if (g != cur) {
            atomicAdd(&pooled[(size_t)cur * H_DIM + t], acc);
            acc = 0.f;
            cur = g;
        }
        acc += h[(size_t)i * H_DIM + t];
    }
    atomicAdd(&pooled[(size_t)cur * H_DIM + t], acc);
}

__global__ void cnt_kernel(const int* __restrict__ batch, float* __restrict__ cnt, int n) {
    int i = blockIdx.x * blockDim.x + threadIdx.x;
    if (i < n) atomicAdd(&cnt[batch[i]], 1.0f);
}

// ---------------- FC head: one block per graph ----------------

__global__ __launch_bounds__(256) void fc_kernel(const float* __restrict__ pooled,
                                                 const float* __restrict__ cnt,
                                                 const float* __restrict__ gattr,
                                                 const float* __restrict__ fcW1,
                                                 const float* __restrict__ fcb1,
                                                 const float* __restrict__ fcW2,
                                                 const float* __restrict__ fcb2,
                                                 float* __restrict__ out) {
    __shared__ float zc[H_DIM + A_DIM];
    __shared__ float z1[H_DIM];
    int g = blockIdx.x, t = threadIdx.x;
    float c = fmaxf(cnt[g], 1.f);
    zc[t] = pooled[(size_t)g * H_DIM + t] / c;
    if (t < A_DIM) zc[H_DIM + t] = gattr[g * A_DIM + t];
    __syncthreads();
    float s = fcb1[t];
    for (int k = 0; k < H_DIM + A_DIM; k++)
        s += zc[k] * fcW1[(size_t)k * H_DIM + t];
    z1[t] = fmaxf(s, 0.f) * fcW2[t];
    __syncthreads();
    for (int off = 128; off; off >>= 1) {
        if (t < off) z1[t] += z1[t + off];
        __syncthreads();
    }
    if (t == 0) out[g] = z1[0] + fcb2[0];
}

// ---------------- launch ----------------

extern "C" void kernel_launch(void* const* d_in, const int* in_sizes, int n_in,
                              void* d_out, int out_size, void* d_ws, size_t ws_size,
                              hipStream_t stream) {
    const float* x     = (const float*)d_in[0];
    const float* gattr = (const float*)d_in[1];
    const int*   ei    = (const int*)d_in[2];
    const int*   batch = (const int*)d_in[3];
    const float* W1 = (const float*)d_in[4];  const float* b1 = (const float*)d_in[5];
    const float* W2 = (const float*)d_in[6];  const float* b2 = (const float*)d_in[7];
    const float* W3 = (const float*)d_in[8];  const float* b3 = (const float*)d_in[9];
    const float* g1 = (const float*)d_in[10]; const float* be1 = (const float*)d_in[11];
    const float* g2 = (const float*)d_in[12]; const float* be2 = (const float*)d_in[13];
    const float* g3 = (const float*)d_in[14]; const float* be3 = (const float*)d_in[15];
    const float* fcW1 = (const float*)d_in[16]; const float* fcb1 = (const float*)d_in[17];
    const float* fcW2 = (const float*)d_in[18]; const float* fcb2 = (const float*)d_in[19];
    float* out = (float*)d_out;

    float* ws    = (float*)d_ws;
    float* P     = ws;                                  // N*H  (xw)
    float* Q     = P + (size_t)N_NODES * H_DIM;         // N*H  (agg / h)
    float* dinv  = Q + (size_t)N_NODES * H_DIM;         // N
    float* pooled = dinv + N_NODES;                     // G*H
    float* cnt   = pooled + (size_t)G_NUM * H_DIM;      // G
    const int* srcp = ei;
    const int* dstp = ei + N_EDGES;

    // degrees -> dinv (in place)
    fill_kernel<<<(N_NODES + 255) / 256, 256, 0, stream>>>(dinv, 1.0f, N_NODES);
    deg_kernel<<<(N_EDGES + 255) / 256, 256, 0, stream>>>(dstp, dinv, N_EDGES);
    dinv_kernel<<<(N_NODES + 255) / 256, 256, 0, stream>>>(dinv, N_NODES);
    hipMemsetAsync(pooled, 0, (size_t)(G_NUM * H_DIM + G_NUM) * sizeof(float), stream);

    dim3 gemm_grid((N_NODES + 63) / 64, H_DIM / 64);
    int sl_blocks = (int)(((size_t)N_NODES * (H_DIM / 4) + 255) / 256);
    int sc_blocks = (N_EDGES + 3) / 4;

    // ---- layer 1 ----
    sgemm64<<<gemm_grid, 256, 0, stream>>>(x, W1, P, N_NODES, F_IN);
    selfloop_kernel<<<sl_blocks, 256, 0, stream>>>(P, Q, dinv, N_NODES);
    scatter_kernel<<<sc_blocks, 256, 0, stream>>>(P, Q, srcp, dstp, dinv, N_EDGES);
    ln_relu_kernel<<<N_NODES, 256, 0, stream>>>(Q, b1, g1, be1);

    // ---- layer 2 ----
    sgemm64<<<gemm_grid, 256, 0, stream>>>(Q, W2, P, N_NODES, H_DIM);
    selfloop_kernel<<<sl_blocks, 256, 0, stream>>>(P, Q, dinv, N_NODES);
    scatter_kernel<<<sc_blocks, 256, 0, stream>>>(P, Q, srcp, dstp, dinv, N_EDGES);
    ln_relu_kernel<<<N_NODES, 256, 0, stream>>>(Q, b2, g2, be2);

    // ---- layer 3 ----
    sgemm64<<<gemm_grid, 256, 0, stream>>>(Q, W3, P, N_NODES, H_DIM);
    selfloop_kernel<<<sl_blocks, 256, 0, stream>>>(P, Q, dinv, N_NODES);
    scatter_kernel<<<sc_blocks, 256, 0, stream>>>(P, Q, srcp, dstp, dinv, N_EDGES);
    ln_relu_kernel<<<N_NODES, 256, 0, stream>>>(Q, b3, g3, be3);

    // ---- pool + FC head ----
    pool_kernel<<<(N_NODES + 63) / 64, 256, 0, stream>>>(Q, batch, pooled, N_NODES);
    cnt_kernel<<<(N_NODES + 255) / 256, 256, 0, stream>>>(batch, cnt, N_NODES);
    fc_kernel<<<G_NUM, 256, 0, stream>>>(pooled, cnt, gattr, fcW1, fcb1, fcW2, fcb2, out);
}

// Round 2
// 1152.525 us; speedup vs baseline: 7.5891x; 7.5891x over previous
//
#include <hip/hip_runtime.h>
#include <hip/hip_bf16.h>

#define N_NODES 50000
#define N_EDGES 800000
#define F_IN    128
#define H_DIM   256
#define G_NUM   64
#define A_DIM   8

// ---------------- CSR build ----------------

__global__ void indeg_kernel(const int* __restrict__ dst, int* __restrict__ indeg, int e) {
    int i = blockIdx.x * blockDim.x + threadIdx.x;
    if (i < e) atomicAdd(&indeg[dst[i]], 1);
}

// dinv[i] = rsqrt(indeg[i] + 1)   (+1 = self-loop)
__global__ void dinv_kernel(const int* __restrict__ indeg, float* __restrict__ dinv, int n) {
    int i = blockIdx.x * blockDim.x + threadIdx.x;
    if (i < n) dinv[i] = rsqrtf((float)indeg[i] + 1.0f);
}

// single-block exclusive scan of indeg -> rowptr  (n ~ 50k, once per call)
__global__ __launch_bounds__(1024) void scan_kernel(const int* __restrict__ indeg,
                                                    int* __restrict__ rowptr, int n) {
    __shared__ int tile[1024];
    __shared__ int carry;
    int t = threadIdx.x;
    if (t == 0) carry = 0;
    __syncthreads();
    for (int base = 0; base < n; base += 1024) {
        int i = base + t;
        int v = (i < n) ? indeg[i] : 0;
        tile[t] = v;
        __syncthreads();
        #pragma unroll
        for (int o = 1; o < 1024; o <<= 1) {
            int add = (t >= o) ? tile[t - o] : 0;
            __syncthreads();
            tile[t] += add;
            __syncthreads();
        }
        if (i < n) rowptr[i] = carry + tile[t] - v;   // exclusive
        int total = tile[1023];
        __syncthreads();
        if (t == 0) carry += total;
        __syncthreads();
    }
    if (t == 0) rowptr[n] = carry;
}

__global__ void copy_pos_kernel(const int* __restrict__ rowptr, int* __restrict__ pos, int n) {
    int i = blockIdx.x * blockDim.x + threadIdx.x;
    if (i < n) pos[i] = rowptr[i];
}

__global__ void place_kernel(const int* __restrict__ src, const int* __restrict__ dst,
                             int* __restrict__ pos, int* __restrict__ csr_src,
                             float* __restrict__ csr_w, const float* __restrict__ dinv, int e) {
    int i = blockIdx.x * blockDim.x + threadIdx.x;
    if (i < e) {
        int s = src[i], d = dst[i];
        int slot = atomicAdd(&pos[d], 1);
        csr_src[slot] = s;
        csr_w[slot] = dinv[s];
    }
}

// ---------------- SGEMM: C[M,256] = A[M,K] @ B[K,256] (row-major, no bias) ----

__global__ __launch_bounds__(256) void sgemm64(const float* __restrict__ A,
                                               const float* __restrict__ B,
                                               float* __restrict__ C,
                                               int M, int K) {
    __shared__ float As[16][68];
    __shared__ float Bs[16][64];
    int tid = threadIdx.x;
    int tx = tid & 15, ty = tid >> 4;
    int bm = blockIdx.x * 64;
    int bn = blockIdx.y * 64;
    float acc[4][4] = {};
    for (int k0 = 0; k0 < K; k0 += 16) {
        {
            int k = tid & 15;
            int m0 = tid >> 4;
            #pragma unroll
            for (int i = 0; i < 4; i++) {
                int m = m0 + i * 16;
                int row = bm + m;
                As[k][m] = (row < M) ? A[(size_t)row * K + k0 + k] : 0.f;
            }
        }
        {
            int n = tid & 63;
            int k1 = tid >> 6;
            #pragma unroll
            for (int i = 0; i < 4; i++) {
                int k = k1 + i * 4;
                Bs[k][n] = B[(size_t)(k0 + k) * H_DIM + bn + n];
            }
        }
        __syncthreads();
        #pragma unroll
        for (int k = 0; k < 16; k++) {
            float4 a = *(const float4*)&As[k][ty * 4];
            float4 b = *(const float4*)&Bs[k][tx * 4];
            float av[4] = {a.x, a.y, a.z, a.w};
            float bv[4] = {b.x, b.y, b.z, b.w};
            #pragma unroll
            for (int i = 0; i < 4; i++)
                #pragma unroll
                for (int j = 0; j < 4; j++)
                    acc[i][j] += av[i] * bv[j];
        }
        __syncthreads();
    }
    #pragma unroll
    for (int i = 0; i < 4; i++) {
        int row = bm + ty * 4 + i;
        if (row < M) {
            float4 v = make_float4(acc[i][0], acc[i][1], acc[i][2], acc[i][3]);
            *(float4*)&C[(size_t)row * H_DIM + bn + tx * 4] = v;
        }
    }
}

// ---------------- fused gather + self-loop + bias + LayerNorm + ReLU ----------------
// one block (256 threads) per destination node; thread t owns feature t

__global__ __launch_bounds__(256) void gather_ln_relu(const float* __restrict__ xw,
                                                      float* __restrict__ out,
                                                      const int* __restrict__ rowptr,
                                                      const int* __restrict__ csr_src,
                                                      const float* __restrict__ csr_w,
                                                      const float* __restrict__ dinv,
                                                      const float* __restrict__ bias,
                                                      const float* __restrict__ gamma,
                                                      const float* __restrict__ beta) {
    int node = blockIdx.x;
    int t = threadIdx.x;
    int beg = rowptr[node], end = rowptr[node + 1];
    __shared__ int   s_src[256];
    __shared__ float s_w[256];
    float acc = 0.f;
    for (int base = beg; base < end; base += 256) {
        int m = end - base; if (m > 256) m = 256;
        __syncthreads();
        if (t < m) { s_src[t] = csr_src[base + t]; s_w[t] = csr_w[base + t]; }
        __syncthreads();
        for (int j = 0; j < m; j++)
            acc = fmaf(s_w[j], xw[(size_t)s_src[j] * H_DIM + t], acc);
    }
    float d = dinv[node];
    float v = d * (acc + d * xw[(size_t)node * H_DIM + t]) + bias[t];

    // LayerNorm over 256 features + ReLU
    float s = v, ss = v * v;
    #pragma unroll
    for (int o = 32; o; o >>= 1) {
        s  += __shfl_down(s, o, 64);
        ss += __shfl_down(ss, o, 64);
    }
    __shared__ float rs[4], rss[4];
    __shared__ float mean_s, rstd_s;
    int wid = t >> 6, lane = t & 63;
    if (lane == 0) { rs[wid] = s; rss[wid] = ss; }
    __syncthreads();
    if (t == 0) {
        float S  = rs[0] + rs[1] + rs[2] + rs[3];
        float SS = rss[0] + rss[1] + rss[2] + rss[3];
        float m = S * (1.f / H_DIM);
        float var = SS * (1.f / H_DIM) - m * m;
        mean_s = m;
        rstd_s = rsqrtf(var + 1e-5f);
    }
    __syncthreads();
    float o = (v - mean_s) * rstd_s * gamma[t] + beta[t];
    out[(size_t)node * H_DIM + t] = fmaxf(o, 0.f);
}

// ---------------- pooling ----------------

__global__ __launch_bounds__(256) void pool_kernel(const float* __restrict__ h,
                                                   const int* __restrict__ batch,
                                                   float* __restrict__ pooled, int n) {
    int t = threadIdx.x;
    int start = blockIdx.x * 64;
    int end = min(start + 64, n);
    if (start >= n) return;
    int cur = batch[start];
    float acc = 0.f;
    for (int i = start; i < end; ++i) {
        int g = batch[i];
        if (g != cur) {
            atomicAdd(&pooled[(size_t)cur * H_DIM + t], acc);
            acc = 0.f;
            cur = g;
        }
        acc += h[(size_t)i * H_DIM + t];
    }
    atomicAdd(&pooled[(size_t)cur * H_DIM + t], acc);
}

__global__ void cnt_kernel(const int* __restrict__ batch, float* __restrict__ cnt, int n) {
    int i = blockIdx.x * blockDim.x + threadIdx.x;
    if (i < n) atomicAdd(&cnt[batch[i]], 1.0f);
}

// ---------------- FC head ----------------

__global__ __launch_bounds__(256) void fc_kernel(const float* __restrict__ pooled,
                                                 const float* __restrict__ cnt,
                                                 const float* __restrict__ gattr,
                                                 const float* __restrict__ fcW1,
                                                 const float* __restrict__ fcb1,
                                                 const float* __restrict__ fcW2,
                                                 const float* __restrict__ fcb2,
                                                 float* __restrict__ out) {
    __shared__ float zc[H_DIM + A_DIM];
    __shared__ float z1[H_DIM];
    int g = blockIdx.x, t = threadIdx.x;
    float c = fmaxf(cnt[g], 1.f);
    zc[t] = pooled[(size_t)g * H_DIM + t] / c;
    if (t < A_DIM) zc[H_DIM + t] = gattr[g * A_DIM + t];
    __syncthreads();
    float s = fcb1[t];
    for (int k = 0; k < H_DIM + A_DIM; k++)
        s += zc[k] * fcW1[(size_t)k * H_DIM + t];
    z1[t] = fmaxf(s, 0.f) * fcW2[t];
    __syncthreads();
    for (int off = 128; off; off >>= 1) {
        if (t < off) z1[t] += z1[t + off];
        __syncthreads();
    }
    if (t == 0) out[g] = z1[0] + fcb2[0];
}

// ---------------- launch ----------------

extern "C" void kernel_launch(void* const* d_in, const int* in_sizes, int n_in,
                              void* d_out, int out_size, void* d_ws, size_t ws_size,
                              hipStream_t stream) {
    const float* x     = (const float*)d_in[0];
    const float* gattr = (const float*)d_in[1];
    const int*   ei    = (const int*)d_in[2];
    const int*   batch = (const int*)d_in[3];
    const float* W1 = (const float*)d_in[4];  const float* b1 = (const float*)d_in[5];
    const float* W2 = (const float*)d_in[6];  const float* b2 = (const float*)d_in[7];
    const float* W3 = (const float*)d_in[8];  const float* b3 = (const float*)d_in[9];
    const float* g1 = (const float*)d_in[10]; const float* be1 = (const float*)d_in[11];
    const float* g2 = (const float*)d_in[12]; const float* be2 = (const float*)d_in[13];
    const float* g3 = (const float*)d_in[14]; const float* be3 = (const float*)d_in[15];
    const float* fcW1 = (const float*)d_in[16]; const float* fcb1 = (const float*)d_in[17];
    const float* fcW2 = (const float*)d_in[18]; const float* fcb2 = (const float*)d_in[19];
    float* out = (float*)d_out;

    float* ws     = (float*)d_ws;
    float* P      = ws;                                   // N*H  (xw)
    float* Q      = P + (size_t)N_NODES * H_DIM;          // N*H  (h)
    float* dinv   = Q + (size_t)N_NODES * H_DIM;          // N
    float* pooled = dinv + N_NODES;                       // G*H
    float* cnt    = pooled + (size_t)G_NUM * H_DIM;       // G
    float* csr_w  = cnt + G_NUM;                          // E
    int*   indeg  = (int*)(csr_w + N_EDGES);              // N
    int*   rowptr = indeg + N_NODES;                      // N+1
    int*   pos    = rowptr + N_NODES + 1;                 // N
    int*   csr_src = pos + N_NODES;                       // E

    const int* srcp = ei;
    const int* dstp = ei + N_EDGES;

    // ---- CSR build ----
    hipMemsetAsync(indeg, 0, (size_t)N_NODES * sizeof(int), stream);
    hipMemsetAsync(pooled, 0, (size_t)(G_NUM * H_DIM + G_NUM) * sizeof(float), stream);
    indeg_kernel<<<(N_EDGES + 255) / 256, 256, 0, stream>>>(dstp, indeg, N_EDGES);
    dinv_kernel<<<(N_NODES + 255) / 256, 256, 0, stream>>>(indeg, dinv, N_NODES);
    scan_kernel<<<1, 1024, 0, stream>>>(indeg, rowptr, N_NODES);
    copy_pos_kernel<<<(N_NODES + 255) / 256, 256, 0, stream>>>(rowptr, pos, N_NODES);
    place_kernel<<<(N_EDGES + 255) / 256, 256, 0, stream>>>(srcp, dstp, pos, csr_src, csr_w, dinv, N_EDGES);

    dim3 gemm_grid((N_NODES + 63) / 64, H_DIM / 64);

    // ---- layer 1 ----
    sgemm64<<<gemm_grid, 256, 0, stream>>>(x, W1, P, N_NODES, F_IN);
    gather_ln_relu<<<N_NODES, 256, 0, stream>>>(P, Q, rowptr, csr_src, csr_w, dinv, b1, g1, be1);
    // ---- layer 2 ----
    sgemm64<<<gemm_grid, 256, 0, stream>>>(Q, W2, P, N_NODES, H_DIM);
    gather_ln_relu<<<N_NODES, 256, 0, stream>>>(P, Q, rowptr, csr_src, csr_w, dinv, b2, g2, be2);
    // ---- layer 3 ----
    sgemm64<<<gemm_grid, 256, 0, stream>>>(Q, W3, P, N_NODES, H_DIM);
    gather_ln_relu<<<N_NODES, 256, 0, stream>>>(P, Q, rowptr, csr_src, csr_w, dinv, b3, g3, be3);

    // ---- pool + FC head ----
    pool_kernel<<<(N_NODES + 63) / 64, 256, 0, stream>>>(Q, batch, pooled, N_NODES);
    cnt_kernel<<<(N_NODES + 255) / 256, 256, 0, stream>>>(batch, cnt, N_NODES);
    fc_kernel<<<G_NUM, 256, 0, stream>>>(pooled, cnt, gattr, fcW1, fcb1, fcW2, fcb2, out);
}

// Round 3
// 720.324 us; speedup vs baseline: 12.1426x; 1.6000x over previous
//
#include <hip/hip_runtime.h>
#include <hip/hip_bf16.h>

#define N_NODES 50000
#define N_EDGES 800000
#define F_IN    128
#define H_DIM   256
#define G_NUM   64
#define A_DIM   8

typedef __attribute__((ext_vector_type(8))) short short8v;
typedef __attribute__((ext_vector_type(4))) float float4v;

// ---------------- CSR build ----------------

__global__ void indeg_kernel(const int* __restrict__ dst, int* __restrict__ indeg, int e) {
    int i = blockIdx.x * blockDim.x + threadIdx.x;
    if (i < e) atomicAdd(&indeg[dst[i]], 1);
}

__global__ void dinv_kernel(const int* __restrict__ indeg, float* __restrict__ dinv, int n) {
    int i = blockIdx.x * blockDim.x + threadIdx.x;
    if (i < n) dinv[i] = rsqrtf((float)indeg[i] + 1.0f);
}

__global__ __launch_bounds__(1024) void scan_kernel(const int* __restrict__ indeg,
                                                    int* __restrict__ rowptr, int n) {
    __shared__ int tile[1024];
    __shared__ int carry;
    int t = threadIdx.x;
    if (t == 0) carry = 0;
    __syncthreads();
    for (int base = 0; base < n; base += 1024) {
        int i = base + t;
        int v = (i < n) ? indeg[i] : 0;
        tile[t] = v;
        __syncthreads();
        #pragma unroll
        for (int o = 1; o < 1024; o <<= 1) {
            int add = (t >= o) ? tile[t - o] : 0;
            __syncthreads();
            tile[t] += add;
            __syncthreads();
        }
        if (i < n) rowptr[i] = carry + tile[t] - v;
        int total = tile[1023];
        __syncthreads();
        if (t == 0) carry += total;
        __syncthreads();
    }
    if (t == 0) rowptr[n] = carry;
}

__global__ void copy_pos_kernel(const int* __restrict__ rowptr, int* __restrict__ pos, int n) {
    int i = blockIdx.x * blockDim.x + threadIdx.x;
    if (i < n) pos[i] = rowptr[i];
}

__global__ void place_kernel(const int* __restrict__ src, const int* __restrict__ dst,
                             int* __restrict__ pos, int* __restrict__ csr_src,
                             float* __restrict__ csr_w, const float* __restrict__ dinv, int e) {
    int i = blockIdx.x * blockDim.x + threadIdx.x;
    if (i < e) {
        int s = src[i], d = dst[i];
        int slot = atomicAdd(&pos[d], 1);
        csr_src[slot] = s;
        csr_w[slot] = dinv[s];
    }
}

// gstart[g] = lower_bound(batch, g), g in [0, G]  (batch is sorted)
__global__ void bounds_kernel(const int* __restrict__ batch, int* __restrict__ gstart) {
    int g = threadIdx.x;
    if (g > G_NUM) return;
    int lo = 0, hi = N_NODES;
    while (lo < hi) {
        int mid = (lo + hi) >> 1;
        if (batch[mid] < g) lo = mid + 1; else hi = mid;
    }
    gstart[g] = lo;
}

// ---------------- conversions ----------------

__global__ void xconv_kernel(const float* __restrict__ x, __hip_bfloat16* __restrict__ xb, int n) {
    int i = blockIdx.x * blockDim.x + threadIdx.x;
    if (i < n) xb[i] = __float2bfloat16(x[i]);
}

// W [K][Nn] fp32 -> Wt [Nn][K] bf16
__global__ void wconv_kernel(const float* __restrict__ W, __hip_bfloat16* __restrict__ Wt,
                             int K, int Nn) {
    int i = blockIdx.x * blockDim.x + threadIdx.x;
    if (i < K * Nn) {
        int k = i / Nn, n = i % Nn;
        Wt[(size_t)n * K + k] = __float2bfloat16(W[i]);
    }
}

// ---------------- bf16 MFMA GEMM: C[M,256] = A[M,K] @ Bt[256,K]^T ----------------
// block = 256 threads = 4 waves (2x2), tile 128x128, BK=32

#define SK 40   // padded LDS stride (2-way max bank aliasing = free)

__global__ __launch_bounds__(256) void gemm_bf16(const __hip_bfloat16* __restrict__ Ab,
                                                 const __hip_bfloat16* __restrict__ Btb,
                                                 __hip_bfloat16* __restrict__ C,
                                                 int M, int K) {
    __shared__ unsigned short As[128][SK];
    __shared__ unsigned short Bs[128][SK];
    const unsigned short* A  = (const unsigned short*)Ab;
    const unsigned short* Bt = (const unsigned short*)Btb;
    int t = threadIdx.x;
    int wave = t >> 6, lane = t & 63;
    int wm0 = (wave & 1) * 64, wn0 = (wave >> 1) * 64;
    int bm = blockIdx.x * 128, bn = blockIdx.y * 128;
    int l15 = lane & 15, lq = lane >> 4;
    float4v acc[4][4];
    #pragma unroll
    for (int i = 0; i < 4; i++)
        #pragma unroll
        for (int j = 0; j < 4; j++)
            acc[i][j] = (float4v){0.f, 0.f, 0.f, 0.f};

    for (int k0 = 0; k0 < K; k0 += 32) {
        #pragma unroll
        for (int h = 0; h < 2; h++) {
            int c = t + h * 256;           // 512 chunks of 8 bf16
            int row = c >> 2, koff = (c & 3) * 8;
            uint4 va = make_uint4(0u, 0u, 0u, 0u);
            if (bm + row < M)
                va = *(const uint4*)(A + (size_t)(bm + row) * K + k0 + koff);
            *(uint4*)&As[row][koff] = va;
            uint4 vb = *(const uint4*)(Bt + (size_t)(bn + row) * K + k0 + koff);
            *(uint4*)&Bs[row][koff] = vb;
        }
        __syncthreads();
        short8v af[4], bf[4];
        #pragma unroll
        for (int i = 0; i < 4; i++) {
            af[i] = *(const short8v*)&As[wm0 + i * 16 + l15][lq * 8];
            bf[i] = *(const short8v*)&Bs[wn0 + i * 16 + l15][lq * 8];
        }
        #pragma unroll
        for (int i = 0; i < 4; i++)
            #pragma unroll
            for (int j = 0; j < 4; j++)
                acc[i][j] = __builtin_amdgcn_mfma_f32_16x16x32_bf16(af[i], bf[j], acc[i][j], 0, 0, 0);
        __syncthreads();
    }
    // epilogue: C/D layout col = lane&15, row = (lane>>4)*4 + reg
    #pragma unroll
    for (int i = 0; i < 4; i++) {
        #pragma unroll
        for (int r = 0; r < 4; r++) {
            int row = bm + wm0 + i * 16 + lq * 4 + r;
            if (row < M) {
                #pragma unroll
                for (int j = 0; j < 4; j++) {
                    int col = bn + wn0 + j * 16 + l15;
                    C[(size_t)row * H_DIM + col] = __float2bfloat16(acc[i][j][r]);
                }
            }
        }
    }
}

// ---------------- fused gather + self-loop + bias + LayerNorm + ReLU ----------------
// one block (256 threads) per destination node; thread t owns feature t

__global__ __launch_bounds__(256) void gather_ln_relu(const __hip_bfloat16* __restrict__ xw,
                                                      __hip_bfloat16* __restrict__ out,
                                                      const int* __restrict__ rowptr,
                                                      const int* __restrict__ csr_src,
                                                      const float* __restrict__ csr_w,
                                                      const float* __restrict__ dinv,
                                                      const float* __restrict__ bias,
                                                      const float* __restrict__ gamma,
                                                      const float* __restrict__ beta) {
    int node = blockIdx.x;
    int t = threadIdx.x;
    int beg = rowptr[node], end = rowptr[node + 1];
    __shared__ int   s_src[256];
    __shared__ float s_w[256];
    float acc = 0.f;
    for (int base = beg; base < end; base += 256) {
        int m = end - base; if (m > 256) m = 256;
        __syncthreads();
        if (t < m) { s_src[t] = csr_src[base + t]; s_w[t] = csr_w[base + t]; }
        __syncthreads();
        for (int j = 0; j < m; j++)
            acc = fmaf(s_w[j], __bfloat162float(xw[(size_t)s_src[j] * H_DIM + t]), acc);
    }
    float d = dinv[node];
    float v = d * (acc + d * __bfloat162float(xw[(size_t)node * H_DIM + t])) + bias[t];

    float s = v, ss = v * v;
    #pragma unroll
    for (int o = 32; o; o >>= 1) {
        s  += __shfl_down(s, o, 64);
        ss += __shfl_down(ss, o, 64);
    }
    __shared__ float rs[4], rss[4];
    __shared__ float mean_s, rstd_s;
    int wid = t >> 6, lane = t & 63;
    if (lane == 0) { rs[wid] = s; rss[wid] = ss; }
    __syncthreads();
    if (t == 0) {
        float S  = rs[0] + rs[1] + rs[2] + rs[3];
        float SS = rss[0] + rss[1] + rss[2] + rss[3];
        float m = S * (1.f / H_DIM);
        float var = SS * (1.f / H_DIM) - m * m;
        mean_s = m;
        rstd_s = rsqrtf(var + 1e-5f);
    }
    __syncthreads();
    float o = (v - mean_s) * rstd_s * gamma[t] + beta[t];
    out[(size_t)node * H_DIM + t] = __float2bfloat16(fmaxf(o, 0.f));
}

// ---------------- pooling ----------------

__global__ __launch_bounds__(256) void pool_kernel(const __hip_bfloat16* __restrict__ h,
                                                   const int* __restrict__ batch,
                                                   float* __restrict__ pooled, int n) {
    int t = threadIdx.x;
    int start = blockIdx.x * 64;
    int end = min(start + 64, n);
    if (start >= n) return;
    int cur = batch[start];
    float acc = 0.f;
    for (int i = start; i < end; ++i) {
        int g = batch[i];
        if (g != cur) {
            atomicAdd(&pooled[(size_t)cur * H_DIM + t], acc);
            acc = 0.f;
            cur = g;
        }
        acc += __bfloat162float(h[(size_t)i * H_DIM + t]);
    }
    atomicAdd(&pooled[(size_t)cur * H_DIM + t], acc);
}

// ---------------- FC head ----------------

__global__ __launch_bounds__(256) void fc_kernel(const float* __restrict__ pooled,
                                                 const int* __restrict__ gstart,
                                                 const float* __restrict__ gattr,
                                                 const float* __restrict__ fcW1,
                                                 const float* __restrict__ fcb1,
                                                 const float* __restrict__ fcW2,
                                                 const float* __restrict__ fcb2,
                                                 float* __restrict__ out) {
    __shared__ float zc[H_DIM + A_DIM];
    __shared__ float z1[H_DIM];
    int g = blockIdx.x, t = threadIdx.x;
    int c_i = gstart[g + 1] - gstart[g];
    float c = (float)(c_i > 1 ? c_i : 1);
    zc[t] = pooled[(size_t)g * H_DIM + t] / c;
    if (t < A_DIM) zc[H_DIM + t] = gattr[g * A_DIM + t];
    __syncthreads();
    float s = fcb1[t];
    for (int k = 0; k < H_DIM + A_DIM; k++)
        s += zc[k] * fcW1[(size_t)k * H_DIM + t];
    z1[t] = fmaxf(s, 0.f) * fcW2[t];
    __syncthreads();
    for (int off = 128; off; off >>= 1) {
        if (t < off) z1[t] += z1[t + off];
        __syncthreads();
    }
    if (t == 0) out[g] = z1[0] + fcb2[0];
}

// ---------------- launch ----------------

extern "C" void kernel_launch(void* const* d_in, const int* in_sizes, int n_in,
                              void* d_out, int out_size, void* d_ws, size_t ws_size,
                              hipStream_t stream) {
    const float* x     = (const float*)d_in[0];
    const float* gattr = (const float*)d_in[1];
    const int*   ei    = (const int*)d_in[2];
    const int*   batch = (const int*)d_in[3];
    const float* W1 = (const float*)d_in[4];  const float* b1 = (const float*)d_in[5];
    const float* W2 = (const float*)d_in[6];  const float* b2 = (const float*)d_in[7];
    const float* W3 = (const float*)d_in[8];  const float* b3 = (const float*)d_in[9];
    const float* g1 = (const float*)d_in[10]; const float* be1 = (const float*)d_in[11];
    const float* g2 = (const float*)d_in[12]; const float* be2 = (const float*)d_in[13];
    const float* g3 = (const float*)d_in[14]; const float* be3 = (const float*)d_in[15];
    const float* fcW1 = (const float*)d_in[16]; const float* fcb1 = (const float*)d_in[17];
    const float* fcW2 = (const float*)d_in[18]; const float* fcb2 = (const float*)d_in[19];
    float* out = (float*)d_out;

    char* w = (char*)d_ws;
    __hip_bfloat16* Pb  = (__hip_bfloat16*)w; w += (size_t)N_NODES * H_DIM * 2;   // xw (bf16)
    __hip_bfloat16* Hb  = (__hip_bfloat16*)w; w += (size_t)N_NODES * H_DIM * 2;   // h  (bf16)
    __hip_bfloat16* Xb  = (__hip_bfloat16*)w; w += (size_t)N_NODES * F_IN  * 2;   // x  (bf16)
    __hip_bfloat16* Wt1 = (__hip_bfloat16*)w; w += (size_t)H_DIM * F_IN * 2;      // W1^T
    __hip_bfloat16* Wt2 = (__hip_bfloat16*)w; w += (size_t)H_DIM * H_DIM * 2;     // W2^T
    __hip_bfloat16* Wt3 = (__hip_bfloat16*)w; w += (size_t)H_DIM * H_DIM * 2;     // W3^T
    float* dinv   = (float*)w; w += (size_t)N_NODES * 4;
    float* pooled = (float*)w; w += (size_t)G_NUM * H_DIM * 4;
    float* csr_w  = (float*)w; w += (size_t)N_EDGES * 4;
    int* indeg    = (int*)w;   w += (size_t)N_NODES * 4;
    int* rowptr   = (int*)w;   w += (size_t)(N_NODES + 1) * 4;
    int* pos      = (int*)w;   w += (size_t)N_NODES * 4;
    int* csr_src  = (int*)w;   w += (size_t)N_EDGES * 4;
    int* gstart   = (int*)w;   w += (size_t)(G_NUM + 1) * 4;

    const int* srcp = ei;
    const int* dstp = ei + N_EDGES;

    // ---- CSR build + constants ----
    hipMemsetAsync(indeg, 0, (size_t)N_NODES * sizeof(int), stream);
    hipMemsetAsync(pooled, 0, (size_t)G_NUM * H_DIM * sizeof(float), stream);
    indeg_kernel<<<(N_EDGES + 255) / 256, 256, 0, stream>>>(dstp, indeg, N_EDGES);
    dinv_kernel<<<(N_NODES + 255) / 256, 256, 0, stream>>>(indeg, dinv, N_NODES);
    scan_kernel<<<1, 1024, 0, stream>>>(indeg, rowptr, N_NODES);
    copy_pos_kernel<<<(N_NODES + 255) / 256, 256, 0, stream>>>(rowptr, pos, N_NODES);
    place_kernel<<<(N_EDGES + 255) / 256, 256, 0, stream>>>(srcp, dstp, pos, csr_src, csr_w, dinv, N_EDGES);
    bounds_kernel<<<1, 128, 0, stream>>>(batch, gstart);

    // ---- bf16 conversions ----
    xconv_kernel<<<(N_NODES * F_IN + 255) / 256, 256, 0, stream>>>(x, Xb, N_NODES * F_IN);
    wconv_kernel<<<(F_IN * H_DIM + 255) / 256, 256, 0, stream>>>(W1, Wt1, F_IN, H_DIM);
    wconv_kernel<<<(H_DIM * H_DIM + 255) / 256, 256, 0, stream>>>(W2, Wt2, H_DIM, H_DIM);
    wconv_kernel<<<(H_DIM * H_DIM + 255) / 256, 256, 0, stream>>>(W3, Wt3, H_DIM, H_DIM);

    dim3 gemm_grid((N_NODES + 127) / 128, H_DIM / 128);

    // ---- layer 1 ----
    gemm_bf16<<<gemm_grid, 256, 0, stream>>>(Xb, Wt1, Pb, N_NODES, F_IN);
    gather_ln_relu<<<N_NODES, 256, 0, stream>>>(Pb, Hb, rowptr, csr_src, csr_w, dinv, b1, g1, be1);
    // ---- layer 2 ----
    gemm_bf16<<<gemm_grid, 256, 0, stream>>>(Hb, Wt2, Pb, N_NODES, H_DIM);
    gather_ln_relu<<<N_NODES, 256, 0, stream>>>(Pb, Hb, rowptr, csr_src, csr_w, dinv, b2, g2, be2);
    // ---- layer 3 ----
    gemm_bf16<<<gemm_grid, 256, 0, stream>>>(Hb, Wt3, Pb, N_NODES, H_DIM);
    gather_ln_relu<<<N_NODES, 256, 0, stream>>>(Pb, Hb, rowptr, csr_src, csr_w, dinv, b3, g3, be3);

    // ---- pool + FC head ----
    pool_kernel<<<(N_NODES + 63) / 64, 256, 0, stream>>>(Hb, batch, pooled, N_NODES);
    fc_kernel<<<G_NUM, 256, 0, stream>>>(pooled, gstart, gattr, fcW1, fcb1, fcW2, fcb2, out);
}

// Round 4
// 482.364 us; speedup vs baseline: 18.1328x; 1.4933x over previous
//
#include <hip/hip_runtime.h>
#include <hip/hip_bf16.h>

#define N_NODES 50000
#define N_EDGES 800000
#define F_IN    128
#define H_DIM   256
#define G_NUM   64
#define A_DIM   8

typedef __attribute__((ext_vector_type(8))) short short8v;
typedef __attribute__((ext_vector_type(4))) float float4v;

__device__ __forceinline__ float b2f(unsigned short u) {
    return __uint_as_float(((unsigned int)u) << 16);
}

// ---------------- CSR build ----------------

__global__ void indeg_kernel(const int* __restrict__ dst, int* __restrict__ indeg, int e) {
    int i = blockIdx.x * blockDim.x + threadIdx.x;
    if (i < e) atomicAdd(&indeg[dst[i]], 1);
}

__global__ void dinv_kernel(const int* __restrict__ indeg, float* __restrict__ dinv, int n) {
    int i = blockIdx.x * blockDim.x + threadIdx.x;
    if (i < n) dinv[i] = rsqrtf((float)indeg[i] + 1.0f);
}

// multi-block exclusive scan: indeg[n] -> rowptr (3 kernels)
__global__ __launch_bounds__(256) void scan1_kernel(const int* __restrict__ in,
                                                    int* __restrict__ out,
                                                    int* __restrict__ bsum, int n) {
    __shared__ int tile[256];
    int b = blockIdx.x, t = threadIdx.x, i = b * 256 + t;
    int v = (i < n) ? in[i] : 0;
    tile[t] = v;
    __syncthreads();
    #pragma unroll
    for (int o = 1; o < 256; o <<= 1) {
        int add = (t >= o) ? tile[t - o] : 0;
        __syncthreads();
        tile[t] += add;
        __syncthreads();
    }
    if (i < n) out[i] = tile[t] - v;          // block-local exclusive
    if (t == 255) bsum[b] = tile[255];
}

__global__ __launch_bounds__(256) void scan2_kernel(int* __restrict__ bsum, int nb) {
    __shared__ int tile[256];
    int t = threadIdx.x;
    int v = (t < nb) ? bsum[t] : 0;
    tile[t] = v;
    __syncthreads();
    #pragma unroll
    for (int o = 1; o < 256; o <<= 1) {
        int add = (t >= o) ? tile[t - o] : 0;
        __syncthreads();
        tile[t] += add;
        __syncthreads();
    }
    if (t < nb) bsum[t] = tile[t] - v;        // exclusive block offsets
}

__global__ __launch_bounds__(256) void scan3_kernel(int* __restrict__ out,
                                                    const int* __restrict__ bsum, int n) {
    int i = blockIdx.x * blockDim.x + threadIdx.x;
    if (i < n) out[i] += bsum[i >> 8];
    if (i == 0) out[n] = N_EDGES;             // total is known
}

__global__ void copy_pos_kernel(const int* __restrict__ rowptr, int* __restrict__ pos, int n) {
    int i = blockIdx.x * blockDim.x + threadIdx.x;
    if (i < n) pos[i] = rowptr[i];
}

__global__ void place_kernel(const int* __restrict__ src, const int* __restrict__ dst,
                             int* __restrict__ pos, int* __restrict__ csr_src,
                             float* __restrict__ csr_w, const float* __restrict__ dinv, int e) {
    int i = blockIdx.x * blockDim.x + threadIdx.x;
    if (i < e) {
        int s = src[i], d = dst[i];
        int slot = atomicAdd(&pos[d], 1);
        csr_src[slot] = s;
        csr_w[slot] = dinv[s];
    }
}

// gstart[g] = lower_bound(batch, g)
__global__ void bounds_kernel(const int* __restrict__ batch, int* __restrict__ gstart) {
    int g = threadIdx.x;
    if (g > G_NUM) return;
    int lo = 0, hi = N_NODES;
    while (lo < hi) {
        int mid = (lo + hi) >> 1;
        if (batch[mid] < g) lo = mid + 1; else hi = mid;
    }
    gstart[g] = lo;
}

// ---------------- conversions ----------------

__global__ void xconv_kernel(const float4* __restrict__ x, ushort4* __restrict__ xb, int n4) {
    int i = blockIdx.x * blockDim.x + threadIdx.x;
    if (i < n4) {
        float4 v = x[i];
        ushort4 o;
        o.x = __hip_bfloat16_raw(__float2bfloat16(v.x)).x;
        o.y = __hip_bfloat16_raw(__float2bfloat16(v.y)).x;
        o.z = __hip_bfloat16_raw(__float2bfloat16(v.z)).x;
        o.w = __hip_bfloat16_raw(__float2bfloat16(v.w)).x;
        xb[i] = o;
    }
}

// W [K][Nn] fp32 -> Wt [Nn][K] bf16
__global__ void wconv_kernel(const float* __restrict__ W, __hip_bfloat16* __restrict__ Wt,
                             int K, int Nn) {
    int i = blockIdx.x * blockDim.x + threadIdx.x;
    if (i < K * Nn) {
        int k = i / Nn, n = i % Nn;
        Wt[(size_t)n * K + k] = __float2bfloat16(W[i]);
    }
}

// ---------------- bf16 MFMA GEMM: C[M,256] = A[M,K] @ Bt[256,K]^T ----------------

#define SK 40

__global__ __launch_bounds__(256) void gemm_bf16(const __hip_bfloat16* __restrict__ Ab,
                                                 const __hip_bfloat16* __restrict__ Btb,
                                                 __hip_bfloat16* __restrict__ C,
                                                 int M, int K) {
    __shared__ unsigned short As[128][SK];
    __shared__ unsigned short Bs[128][SK];
    const unsigned short* A  = (const unsigned short*)Ab;
    const unsigned short* Bt = (const unsigned short*)Btb;
    int t = threadIdx.x;
    int wave = t >> 6, lane = t & 63;
    int wm0 = (wave & 1) * 64, wn0 = (wave >> 1) * 64;
    int bm = blockIdx.x * 128, bn = blockIdx.y * 128;
    int l15 = lane & 15, lq = lane >> 4;
    float4v acc[4][4];
    #pragma unroll
    for (int i = 0; i < 4; i++)
        #pragma unroll
        for (int j = 0; j < 4; j++)
            acc[i][j] = (float4v){0.f, 0.f, 0.f, 0.f};

    for (int k0 = 0; k0 < K; k0 += 32) {
        #pragma unroll
        for (int h = 0; h < 2; h++) {
            int c = t + h * 256;
            int row = c >> 2, koff = (c & 3) * 8;
            uint4 va = make_uint4(0u, 0u, 0u, 0u);
            if (bm + row < M)
                va = *(const uint4*)(A + (size_t)(bm + row) * K + k0 + koff);
            *(uint4*)&As[row][koff] = va;
            uint4 vb = *(const uint4*)(Bt + (size_t)(bn + row) * K + k0 + koff);
            *(uint4*)&Bs[row][koff] = vb;
        }
        __syncthreads();
        short8v af[4], bf[4];
        #pragma unroll
        for (int i = 0; i < 4; i++) {
            af[i] = *(const short8v*)&As[wm0 + i * 16 + l15][lq * 8];
            bf[i] = *(const short8v*)&Bs[wn0 + i * 16 + l15][lq * 8];
        }
        #pragma unroll
        for (int i = 0; i < 4; i++)
            #pragma unroll
            for (int j = 0; j < 4; j++)
                acc[i][j] = __builtin_amdgcn_mfma_f32_16x16x32_bf16(af[i], bf[j], acc[i][j], 0, 0, 0);
        __syncthreads();
    }
    #pragma unroll
    for (int i = 0; i < 4; i++) {
        #pragma unroll
        for (int r = 0; r < 4; r++) {
            int row = bm + wm0 + i * 16 + lq * 4 + r;
            if (row < M) {
                #pragma unroll
                for (int j = 0; j < 4; j++) {
                    int col = bn + wn0 + j * 16 + l15;
                    C[(size_t)row * H_DIM + col] = __float2bfloat16(acc[i][j][r]);
                }
            }
        }
    }
}

// -------- fused gather + self-loop + bias + LayerNorm + ReLU (wave-per-node) --------
// 4 waves/block, one node per wave; lane owns features lane*4..lane*4+3

__global__ __launch_bounds__(256) void gather_ln_relu(const ushort4* __restrict__ xw4,
                                                      ushort4* __restrict__ out4,
                                                      const int* __restrict__ rowptr,
                                                      const int* __restrict__ csr_src,
                                                      const float* __restrict__ csr_w,
                                                      const float* __restrict__ dinv,
                                                      const float* __restrict__ bias,
                                                      const float* __restrict__ gamma,
                                                      const float* __restrict__ beta) {
    int wave = threadIdx.x >> 6, lane = threadIdx.x & 63;
    int node = blockIdx.x * 4 + wave;
    if (node >= N_NODES) return;
    int beg = rowptr[node], end = rowptr[node + 1];
    float a0 = 0.f, a1 = 0.f, a2 = 0.f, a3 = 0.f;

    for (int base = beg; base < end; base += 64) {
        int m = end - base; if (m > 64) m = 64;
        int s_reg = 0; float w_reg = 0.f;
        if (lane < m) { s_reg = csr_src[base + lane]; w_reg = csr_w[base + lane]; }
        int j = 0;
        for (; j + 4 <= m; j += 4) {
            int   s0 = __shfl(s_reg, j, 64),     s1 = __shfl(s_reg, j + 1, 64);
            int   s2 = __shfl(s_reg, j + 2, 64), s3 = __shfl(s_reg, j + 3, 64);
            float w0 = __shfl(w_reg, j, 64),     w1 = __shfl(w_reg, j + 1, 64);
            float w2 = __shfl(w_reg, j + 2, 64), w3 = __shfl(w_reg, j + 3, 64);
            ushort4 v0 = xw4[(size_t)s0 * 64 + lane];
            ushort4 v1 = xw4[(size_t)s1 * 64 + lane];
            ushort4 v2 = xw4[(size_t)s2 * 64 + lane];
            ushort4 v3 = xw4[(size_t)s3 * 64 + lane];
            a0 = fmaf(w0, b2f(v0.x), a0); a1 = fmaf(w0, b2f(v0.y), a1);
            a2 = fmaf(w0, b2f(v0.z), a2); a3 = fmaf(w0, b2f(v0.w), a3);
            a0 = fmaf(w1, b2f(v1.x), a0); a1 = fmaf(w1, b2f(v1.y), a1);
            a2 = fmaf(w1, b2f(v1.z), a2); a3 = fmaf(w1, b2f(v1.w), a3);
            a0 = fmaf(w2, b2f(v2.x), a0); a1 = fmaf(w2, b2f(v2.y), a1);
            a2 = fmaf(w2, b2f(v2.z), a2); a3 = fmaf(w2, b2f(v2.w), a3);
            a0 = fmaf(w3, b2f(v3.x), a0); a1 = fmaf(w3, b2f(v3.y), a1);
            a2 = fmaf(w3, b2f(v3.z), a2); a3 = fmaf(w3, b2f(v3.w), a3);
        }
        for (; j < m; j++) {
            int   s = __shfl(s_reg, j, 64);
            float wj = __shfl(w_reg, j, 64);
            ushort4 v = xw4[(size_t)s * 64 + lane];
            a0 = fmaf(wj, b2f(v.x), a0); a1 = fmaf(wj, b2f(v.y), a1);
            a2 = fmaf(wj, b2f(v.z), a2); a3 = fmaf(wj, b2f(v.w), a3);
        }
    }

    float d = dinv[node];
    ushort4 own = xw4[(size_t)node * 64 + lane];
    float4 bi = *(const float4*)&bias[lane * 4];
    float v0 = d * (a0 + d * b2f(own.x)) + bi.x;
    float v1 = d * (a1 + d * b2f(own.y)) + bi.y;
    float v2 = d * (a2 + d * b2f(own.z)) + bi.z;
    float v3 = d * (a3 + d * b2f(own.w)) + bi.w;

    float s  = v0 + v1 + v2 + v3;
    float ss = v0 * v0 + v1 * v1 + v2 * v2 + v3 * v3;
    #pragma unroll
    for (int o = 1; o < 64; o <<= 1) {
        s  += __shfl_xor(s, o, 64);
        ss += __shfl_xor(ss, o, 64);
    }
    float mn = s * (1.f / H_DIM);
    float var = ss * (1.f / H_DIM) - mn * mn;
    float r = rsqrtf(var + 1e-5f);

    float4 ga = *(const float4*)&gamma[lane * 4];
    float4 be = *(const float4*)&beta[lane * 4];
    ushort4 o;
    o.x = __hip_bfloat16_raw(__float2bfloat16(fmaxf((v0 - mn) * r * ga.x + be.x, 0.f))).x;
    o.y = __hip_bfloat16_raw(__float2bfloat16(fmaxf((v1 - mn) * r * ga.y + be.y, 0.f))).x;
    o.z = __hip_bfloat16_raw(__float2bfloat16(fmaxf((v2 - mn) * r * ga.z + be.z, 0.f))).x;
    o.w = __hip_bfloat16_raw(__float2bfloat16(fmaxf((v3 - mn) * r * ga.w + be.w, 0.f))).x;
    out4[(size_t)node * 64 + lane] = o;
}

// ---------------- pooling ----------------

__global__ __launch_bounds__(256) void pool_kernel(const __hip_bfloat16* __restrict__ h,
                                                   const int* __restrict__ batch,
                                                   float* __restrict__ pooled, int n) {
    int t = threadIdx.x;
    int start = blockIdx.x * 64;
    int end = min(start + 64, n);
    if (start >= n) return;
    int cur = batch[start];
    float acc = 0.f;
    for (int i = start; i < end; ++i) {
        int g = batch[i];
        if (g != cur) {
            atomicAdd(&pooled[(size_t)cur * H_DIM + t], acc);
            acc = 0.f;
            cur = g;
        }
        acc += __bfloat162float(h[(size_t)i * H_DIM + t]);
    }
    atomicAdd(&pooled[(size_t)cur * H_DIM + t], acc);
}

// ---------------- FC head ----------------

__global__ __launch_bounds__(256) void fc_kernel(const float* __restrict__ pooled,
                                                 const int* __restrict__ gstart,
                                                 const float* __restrict__ gattr,
                                                 const float* __restrict__ fcW1,
                                                 const float* __restrict__ fcb1,
                                                 const float* __restrict__ fcW2,
                                                 const float* __restrict__ fcb2,
                                                 float* __restrict__ out) {
    __shared__ float zc[H_DIM + A_DIM];
    __shared__ float z1[H_DIM];
    int g = blockIdx.x, t = threadIdx.x;
    int c_i = gstart[g + 1] - gstart[g];
    float c = (float)(c_i > 1 ? c_i : 1);
    zc[t] = pooled[(size_t)g * H_DIM + t] / c;
    if (t < A_DIM) zc[H_DIM + t] = gattr[g * A_DIM + t];
    __syncthreads();
    float s = fcb1[t];
    for (int k = 0; k < H_DIM + A_DIM; k++)
        s += zc[k] * fcW1[(size_t)k * H_DIM + t];
    z1[t] = fmaxf(s, 0.f) * fcW2[t];
    __syncthreads();
    for (int off = 128; off; off >>= 1) {
        if (t < off) z1[t] += z1[t + off];
        __syncthreads();
    }
    if (t == 0) out[g] = z1[0] + fcb2[0];
}

// ---------------- launch ----------------

extern "C" void kernel_launch(void* const* d_in, const int* in_sizes, int n_in,
                              void* d_out, int out_size, void* d_ws, size_t ws_size,
                              hipStream_t stream) {
    const float* x     = (const float*)d_in[0];
    const float* gattr = (const float*)d_in[1];
    const int*   ei    = (const int*)d_in[2];
    const int*   batch = (const int*)d_in[3];
    const float* W1 = (const float*)d_in[4];  const float* b1 = (const float*)d_in[5];
    const float* W2 = (const float*)d_in[6];  const float* b2 = (const float*)d_in[7];
    const float* W3 = (const float*)d_in[8];  const float* b3 = (const float*)d_in[9];
    const float* g1 = (const float*)d_in[10]; const float* be1 = (const float*)d_in[11];
    const float* g2 = (const float*)d_in[12]; const float* be2 = (const float*)d_in[13];
    const float* g3 = (const float*)d_in[14]; const float* be3 = (const float*)d_in[15];
    const float* fcW1 = (const float*)d_in[16]; const float* fcb1 = (const float*)d_in[17];
    const float* fcW2 = (const float*)d_in[18]; const float* fcb2 = (const float*)d_in[19];
    float* out = (float*)d_out;

    char* w = (char*)d_ws;
    __hip_bfloat16* Pb  = (__hip_bfloat16*)w; w += (size_t)N_NODES * H_DIM * 2;
    __hip_bfloat16* Hb  = (__hip_bfloat16*)w; w += (size_t)N_NODES * H_DIM * 2;
    __hip_bfloat16* Xb  = (__hip_bfloat16*)w; w += (size_t)N_NODES * F_IN  * 2;
    __hip_bfloat16* Wt1 = (__hip_bfloat16*)w; w += (size_t)H_DIM * F_IN * 2;
    __hip_bfloat16* Wt2 = (__hip_bfloat16*)w; w += (size_t)H_DIM * H_DIM * 2;
    __hip_bfloat16* Wt3 = (__hip_bfloat16*)w; w += (size_t)H_DIM * H_DIM * 2;
    float* dinv   = (float*)w; w += (size_t)N_NODES * 4;
    float* pooled = (float*)w; w += (size_t)G_NUM * H_DIM * 4;
    float* csr_w  = (float*)w; w += (size_t)N_EDGES * 4;
    int* indeg    = (int*)w;   w += (size_t)N_NODES * 4;
    int* rowptr   = (int*)w;   w += (size_t)(N_NODES + 1) * 4;
    int* pos      = (int*)w;   w += (size_t)N_NODES * 4;
    int* csr_src  = (int*)w;   w += (size_t)N_EDGES * 4;
    int* gstart   = (int*)w;   w += (size_t)(G_NUM + 1) * 4;
    int* bsum     = (int*)w;   w += (size_t)256 * 4;

    const int* srcp = ei;
    const int* dstp = ei + N_EDGES;
    const int n_sblk = (N_NODES + 255) / 256;   // 196

    // ---- CSR build + constants ----
    hipMemsetAsync(indeg, 0, (size_t)N_NODES * sizeof(int), stream);
    hipMemsetAsync(pooled, 0, (size_t)G_NUM * H_DIM * sizeof(float), stream);
    indeg_kernel<<<(N_EDGES + 255) / 256, 256, 0, stream>>>(dstp, indeg, N_EDGES);
    dinv_kernel<<<n_sblk, 256, 0, stream>>>(indeg, dinv, N_NODES);
    scan1_kernel<<<n_sblk, 256, 0, stream>>>(indeg, rowptr, bsum, N_NODES);
    scan2_kernel<<<1, 256, 0, stream>>>(bsum, n_sblk);
    scan3_kernel<<<n_sblk, 256, 0, stream>>>(rowptr, bsum, N_NODES);
    copy_pos_kernel<<<n_sblk, 256, 0, stream>>>(rowptr, pos, N_NODES);
    place_kernel<<<(N_EDGES + 255) / 256, 256, 0, stream>>>(srcp, dstp, pos, csr_src, csr_w, dinv, N_EDGES);
    bounds_kernel<<<1, 128, 0, stream>>>(batch, gstart);

    // ---- bf16 conversions ----
    xconv_kernel<<<(N_NODES * F_IN / 4 + 255) / 256, 256, 0, stream>>>((const float4*)x, (ushort4*)Xb, N_NODES * F_IN / 4);
    wconv_kernel<<<(F_IN * H_DIM + 255) / 256, 256, 0, stream>>>(W1, Wt1, F_IN, H_DIM);
    wconv_kernel<<<(H_DIM * H_DIM + 255) / 256, 256, 0, stream>>>(W2, Wt2, H_DIM, H_DIM);
    wconv_kernel<<<(H_DIM * H_DIM + 255) / 256, 256, 0, stream>>>(W3, Wt3, H_DIM, H_DIM);

    dim3 gemm_grid((N_NODES + 127) / 128, H_DIM / 128);
    int gather_blocks = (N_NODES + 3) / 4;

    // ---- layer 1 ----
    gemm_bf16<<<gemm_grid, 256, 0, stream>>>(Xb, Wt1, Pb, N_NODES, F_IN);
    gather_ln_relu<<<gather_blocks, 256, 0, stream>>>((const ushort4*)Pb, (ushort4*)Hb, rowptr, csr_src, csr_w, dinv, b1, g1, be1);
    // ---- layer 2 ----
    gemm_bf16<<<gemm_grid, 256, 0, stream>>>(Hb, Wt2, Pb, N_NODES, H_DIM);
    gather_ln_relu<<<gather_blocks, 256, 0, stream>>>((const ushort4*)Pb, (ushort4*)Hb, rowptr, csr_src, csr_w, dinv, b2, g2, be2);
    // ---- layer 3 ----
    gemm_bf16<<<gemm_grid, 256, 0, stream>>>(Hb, Wt3, Pb, N_NODES, H_DIM);
    gather_ln_relu<<<gather_blocks, 256, 0, stream>>>((const ushort4*)Pb, (ushort4*)Hb, rowptr, csr_src, csr_w, dinv, b3, g3, be3);

    // ---- pool + FC head ----
    pool_kernel<<<(N_NODES + 63) / 64, 256, 0, stream>>>(Hb, batch, pooled, N_NODES);
    fc_kernel<<<G_NUM, 256, 0, stream>>>(pooled, gstart, gattr, fcW1, fcb1, fcW2, fcb2, out);
}